// Round 3
// baseline (2521.975 us; speedup 1.0000x reference)
//
#include <hip/hip_runtime.h>
#include <math.h>

#define T_LEN 1024
#define D_MODEL 1024
#define NKV 4
#define REP 4
#define DH 64
#define NB 63
#define TOPN 8

// concatenated projection layout (row stride LDIM, per-t)
#define LDIM 1584
#define KCMP_OFF 48
#define VCMP_OFF 304
#define KSLC_OFF 560
#define VSLC_OFF 816
#define KWIN_OFF 1072
#define VWIN_OFF 1328

typedef __attribute__((ext_vector_type(8))) short bf16x8;
typedef __attribute__((ext_vector_type(4))) float f32x4;

__device__ __forceinline__ float gelu_exact(float x) {
    return 0.5f * x * (1.0f + erff(x * 0.70710678118654752f));
}
__device__ __forceinline__ float sigmoidf(float x) {
    return 1.0f / (1.0f + expf(-x));
}
__device__ __forceinline__ unsigned short f2bf(float f) {
    union { float f; unsigned int u; } v; v.f = f;
    unsigned int u = v.u;
    unsigned int r = (u + 0x7FFFu + ((u >> 16) & 1u)) >> 16;  // RNE
    return (unsigned short)r;
}

// ---------------------------------------------------------------------------
// bf16 MFMA GEMM: proj[1024,1584] = x[1024,1024] @ Wcat[1584,1024]^T (+gate_b
// on cols<48). 64x64 tile, BK=32, 4 waves each own 16 rows x 64 cols.
// ---------------------------------------------------------------------------
__global__ __launch_bounds__(256) void proj_gemm(
    const float* __restrict__ x,
    const float* __restrict__ gate_w, const float* __restrict__ gate_b,
    const float* __restrict__ wk_cmp, const float* __restrict__ wv_cmp,
    const float* __restrict__ wk_slc, const float* __restrict__ wv_slc,
    const float* __restrict__ wk_win, const float* __restrict__ wv_win,
    float* __restrict__ proj)
{
    __shared__ unsigned short As[64][40];
    __shared__ unsigned short Bs[64][40];
    const int tid = threadIdx.x;
    const int lane = tid & 63;
    const int w = tid >> 6;
    const int n0 = blockIdx.x * 64;
    const int m0 = blockIdx.y * 64;

    const int srow = tid >> 2;
    const int sseg = tid & 3;
    const float* ga = x + (m0 + srow) * D_MODEL + sseg * 8;
    const float* gb;
    {
        int nn = n0 + srow;
        if (nn < 48) gb = gate_w + nn * D_MODEL;
        else { nn -= 48;
        if (nn < 256) gb = wk_cmp + nn * D_MODEL;
        else { nn -= 256;
        if (nn < 256) gb = wv_cmp + nn * D_MODEL;
        else { nn -= 256;
        if (nn < 256) gb = wk_slc + nn * D_MODEL;
        else { nn -= 256;
        if (nn < 256) gb = wv_slc + nn * D_MODEL;
        else { nn -= 256;
        if (nn < 256) gb = wk_win + nn * D_MODEL;
        else { nn -= 256;
        if (nn < 256) gb = wv_win + nn * D_MODEL;
        else gb = gate_w; }}}}}}
        gb += sseg * 8;
    }

    f32x4 acc[4] = {};
    const int arow = (w << 4) + (lane & 15);
    const int kk8  = (lane >> 4) * 8;

    for (int k0 = 0; k0 < D_MODEL; k0 += 32) {
        float4 a0 = *(const float4*)(ga + k0);
        float4 a1 = *(const float4*)(ga + k0 + 4);
        float4 b0 = *(const float4*)(gb + k0);
        float4 b1 = *(const float4*)(gb + k0 + 4);
        bf16x8 ap, bp;
        ap[0]=(short)f2bf(a0.x); ap[1]=(short)f2bf(a0.y); ap[2]=(short)f2bf(a0.z); ap[3]=(short)f2bf(a0.w);
        ap[4]=(short)f2bf(a1.x); ap[5]=(short)f2bf(a1.y); ap[6]=(short)f2bf(a1.z); ap[7]=(short)f2bf(a1.w);
        bp[0]=(short)f2bf(b0.x); bp[1]=(short)f2bf(b0.y); bp[2]=(short)f2bf(b0.z); bp[3]=(short)f2bf(b0.w);
        bp[4]=(short)f2bf(b1.x); bp[5]=(short)f2bf(b1.y); bp[6]=(short)f2bf(b1.z); bp[7]=(short)f2bf(b1.w);
        __syncthreads();
        *(bf16x8*)&As[srow][sseg * 8] = ap;
        *(bf16x8*)&Bs[srow][sseg * 8] = bp;
        __syncthreads();
        bf16x8 af = *(bf16x8*)&As[arow][kk8];
        #pragma unroll
        for (int j = 0; j < 4; ++j) {
            bf16x8 bfr = *(bf16x8*)&Bs[j * 16 + (lane & 15)][kk8];
            acc[j] = __builtin_amdgcn_mfma_f32_16x16x32_bf16(af, bfr, acc[j], 0, 0, 0);
        }
    }

    #pragma unroll
    for (int j = 0; j < 4; ++j) {
        int col = n0 + j * 16 + (lane & 15);
        if (col >= LDIM) continue;
        float badd = (col < 48) ? gate_b[col] : 0.0f;
        int rbase = m0 + (w << 4) + (lane >> 4) * 4;
        #pragma unroll
        for (int rg = 0; rg < 4; ++rg)
            proj[(rbase + rg) * LDIM + col] = acc[j][rg] + badd;
    }
}

// ---------------------------------------------------------------------------
// f32 GEMM for k_cmp only (selection-critical path stays at f32 precision).
// ---------------------------------------------------------------------------
__global__ __launch_bounds__(256) void gemm_kcmp_f32(
    const float* __restrict__ A, const float* __restrict__ B,
    float* __restrict__ proj)
{
    __shared__ float As[32][68];
    __shared__ float Bs[32][68];
    const int tid = threadIdx.x;
    const int tx = tid & 15, ty = tid >> 4;
    const int n0 = blockIdx.x * 64, m0 = blockIdx.y * 64;
    const int srow = tid >> 2, sseg = tid & 3;
    const float* ga = A + (m0 + srow) * D_MODEL + sseg * 8;
    const float* gb = B + (n0 + srow) * D_MODEL + sseg * 8;

    float acc[4][4] = {};
    for (int k0 = 0; k0 < D_MODEL; k0 += 32) {
        float4 a0 = *(const float4*)(ga + k0);
        float4 a1 = *(const float4*)(ga + k0 + 4);
        float4 b0 = *(const float4*)(gb + k0);
        float4 b1 = *(const float4*)(gb + k0 + 4);
        __syncthreads();
        As[sseg*8+0][srow]=a0.x; As[sseg*8+1][srow]=a0.y; As[sseg*8+2][srow]=a0.z; As[sseg*8+3][srow]=a0.w;
        As[sseg*8+4][srow]=a1.x; As[sseg*8+5][srow]=a1.y; As[sseg*8+6][srow]=a1.z; As[sseg*8+7][srow]=a1.w;
        Bs[sseg*8+0][srow]=b0.x; Bs[sseg*8+1][srow]=b0.y; Bs[sseg*8+2][srow]=b0.z; Bs[sseg*8+3][srow]=b0.w;
        Bs[sseg*8+4][srow]=b1.x; Bs[sseg*8+5][srow]=b1.y; Bs[sseg*8+6][srow]=b1.z; Bs[sseg*8+7][srow]=b1.w;
        __syncthreads();
        #pragma unroll
        for (int kk = 0; kk < 32; ++kk) {
            float4 a4 = *(const float4*)&As[kk][ty * 4];
            float4 b4 = *(const float4*)&Bs[kk][tx * 4];
            acc[0][0] += a4.x*b4.x; acc[0][1] += a4.x*b4.y; acc[0][2] += a4.x*b4.z; acc[0][3] += a4.x*b4.w;
            acc[1][0] += a4.y*b4.x; acc[1][1] += a4.y*b4.y; acc[1][2] += a4.y*b4.z; acc[1][3] += a4.y*b4.w;
            acc[2][0] += a4.z*b4.x; acc[2][1] += a4.z*b4.y; acc[2][2] += a4.z*b4.z; acc[2][3] += a4.z*b4.w;
            acc[3][0] += a4.w*b4.x; acc[3][1] += a4.w*b4.y; acc[3][2] += a4.w*b4.z; acc[3][3] += a4.w*b4.w;
        }
    }
    #pragma unroll
    for (int i = 0; i < 4; ++i) {
        int m = m0 + ty * 4 + i;
        #pragma unroll
        for (int j = 0; j < 4; ++j) {
            int n = n0 + tx * 4 + j;
            proj[m * LDIM + KCMP_OFF + n] = acc[i][j];
        }
    }
}

// ---------------------------------------------------------------------------
// Block summaries from proj columns. grid (63,4,2)
// ---------------------------------------------------------------------------
__global__ __launch_bounds__(256) void nsa_summarize(
    const float* __restrict__ proj, const float* __restrict__ block_pos,
    const float* __restrict__ ck1_w, const float* __restrict__ ck1_b,
    const float* __restrict__ ck2_w, const float* __restrict__ ck2_b,
    const float* __restrict__ cv1_w, const float* __restrict__ cv1_b,
    const float* __restrict__ cv2_w, const float* __restrict__ cv2_b,
    float* __restrict__ ksum, float* __restrict__ vsum)
{
    const int n = blockIdx.x, k = blockIdx.y, which = blockIdx.z;
    const int off  = which ? VCMP_OFF : KCMP_OFF;
    const float* w1 = which ? cv1_w : ck1_w;
    const float* b1 = which ? cv1_b : ck1_b;
    const float* w2 = which ? cv2_w : ck2_w;
    const float* b2 = which ? cv2_b : ck2_b;
    float* dst      = which ? vsum  : ksum;

    __shared__ float flat[32 * DH];
    __shared__ float hidden[DH];
    const int tid = threadIdx.x;
    const int start = n * 16;

    for (int e = tid; e < 512; e += 256) {
        int p = e >> 4, d4 = e & 15;
        float4 s = *(const float4*)(proj + (start + p) * LDIM + off + k * DH + d4 * 4);
        float4 bp = *(const float4*)(block_pos + p * DH + d4 * 4);
        float4 r; r.x = s.x + bp.x; r.y = s.y + bp.y; r.z = s.z + bp.z; r.w = s.w + bp.w;
        *(float4*)&flat[p * DH + d4 * 4] = r;
    }
    __syncthreads();
    {
        int h = tid >> 2, part = tid & 3;
        const float* wr = w1 + h * 2048 + part * 512;
        const float* fl = flat + part * 512;
        float s = 0.0f;
        for (int j = 0; j < 512; j += 4) {
            float4 a = *(const float4*)(fl + j);
            float4 b = *(const float4*)(wr + j);
            s += a.x * b.x + a.y * b.y + a.z * b.z + a.w * b.w;
        }
        s += __shfl_xor(s, 1);
        s += __shfl_xor(s, 2);
        if (part == 0) hidden[h] = gelu_exact(s + b1[h]);
    }
    __syncthreads();
    {
        int dh = tid >> 2, part = tid & 3;
        const float* wr = w2 + dh * 64 + part * 16;
        float s = 0.0f;
        #pragma unroll
        for (int hh = 0; hh < 16; ++hh) s += hidden[part * 16 + hh] * wr[hh];
        s += __shfl_xor(s, 1);
        s += __shfl_xor(s, 2);
        if (part == 0) dst[(n * NKV + k) * DH + dh] = s + b2[dh];
    }
}

// ---------------------------------------------------------------------------
// Fused attention: one workgroup per (t, kv head); wave r = GQA rep r.
// q stays in LDS (wave-uniform broadcast reads); float2 LDS everywhere.
// ---------------------------------------------------------------------------
__global__ __launch_bounds__(256) void nsa_fused(
    const float* __restrict__ q, const float* __restrict__ proj,
    const float* __restrict__ ksum, const float* __restrict__ vsum,
    float* __restrict__ out)
{
    const int t = blockIdx.x, k = blockIdx.y;
    const int tid = threadIdx.x, lane = tid & 63, r = tid >> 6;

    __shared__ float chunk[64][66];
    __shared__ float sc_s[REP][256];
    __shared__ float p_cmp_s[REP][64];
    __shared__ float q_s[REP][DH];
    __shared__ int   sel_s[TOPN];

    // ---- q into LDS ----
    q_s[r][lane] = q[((r * NKV + k) * T_LEN + t) * DH + lane];

    // ---- compressed branch: stage ksum, scores, softmax ----
    for (int e = tid; e < 64 * 32; e += 256) {
        int p = e >> 5, d2 = e & 31;
        int nn = (p < NB) ? p : NB - 1;
        *(float2*)&chunk[p][d2 * 2] = *(const float2*)(ksum + (nn * NKV + k) * DH + d2 * 2);
    }
    __syncthreads();
    float s = -1e30f;
    if (lane < NB && (lane * 16 + 31) <= t) {
        float a = 0.0f;
        #pragma unroll
        for (int d2 = 0; d2 < 32; ++d2) {
            float2 qd = *(const float2*)&q_s[r][d2 * 2];
            float2 cd = *(const float2*)&chunk[lane][d2 * 2];
            a += qd.x * cd.x + qd.y * cd.y;
        }
        s = a * 0.125f;
    }
    float m = s;
    for (int off = 32; off; off >>= 1) m = fmaxf(m, __shfl_xor(m, off));
    float ex = (lane < NB) ? expf(s - m) : 0.0f;
    float sum = ex;
    for (int off = 32; off; off >>= 1) sum += __shfl_xor(sum, off);
    p_cmp_s[r][lane] = ex / sum;   // lane 63 -> 0
    __syncthreads();

    // ---- top-8 (wave 0), stable tie-break on lower index ----
    if (r == 0) {
        float imp = (lane < NB)
            ? (p_cmp_s[0][lane] + p_cmp_s[1][lane] + p_cmp_s[2][lane] + p_cmp_s[3][lane])
            : -1e30f;
        for (int it = 0; it < TOPN; ++it) {
            float v = imp; int i = lane;
            for (int off = 32; off; off >>= 1) {
                float ov = __shfl_xor(v, off);
                int   oi = __shfl_xor(i, off);
                if (ov > v || (ov == v && oi < i)) { v = ov; i = oi; }
            }
            if (lane == 0) sel_s[it] = i;
            if (lane == i) imp = -1e30f;
        }
    }
    __syncthreads();

    // ---- out_cmp: stage vsum, weighted sum ----
    for (int e = tid; e < 64 * 32; e += 256) {
        int p = e >> 5, d2 = e & 31;
        int nn = (p < NB) ? p : NB - 1;
        *(float2*)&chunk[p][d2 * 2] = *(const float2*)(vsum + (nn * NKV + k) * DH + d2 * 2);
    }
    __syncthreads();
    float ocmp = 0.0f;
    if (t >= 31) {
        for (int p0 = 0; p0 < 64; p0 += 4) {   // entry 63 has p_cmp 0
            float4 pv = *(const float4*)&p_cmp_s[r][p0];
            ocmp += pv.x * chunk[p0][lane] + pv.y * chunk[p0+1][lane]
                  + pv.z * chunk[p0+2][lane] + pv.w * chunk[p0+3][lane];
        }
    }

    // ---- selected branch ----
    float oslc = 0.0f;
    for (int c = 0; c < 4; ++c) {
        __syncthreads();
        for (int e = tid; e < 64 * 32; e += 256) {
            int pidx = e >> 5, d2 = e & 31;
            int j = c * 64 + pidx;
            int pos = sel_s[j >> 5] * 16 + (j & 31);
            *(float2*)&chunk[pidx][d2 * 2] =
                *(const float2*)(proj + pos * LDIM + KSLC_OFF + k * DH + d2 * 2);
        }
        __syncthreads();
        int j = c * 64 + lane;
        int pos = sel_s[j >> 5] * 16 + (j & 31);
        float a = 0.0f;
        #pragma unroll
        for (int d2 = 0; d2 < 32; ++d2) {
            float2 qd = *(const float2*)&q_s[r][d2 * 2];
            float2 cd = *(const float2*)&chunk[lane][d2 * 2];
            a += qd.x * cd.x + qd.y * cd.y;
        }
        sc_s[r][j] = (pos <= t) ? a * 0.125f : -1e30f;
    }
    __syncthreads();
    {
        float v0 = sc_s[r][lane],       v1 = sc_s[r][64 + lane];
        float v2 = sc_s[r][128 + lane], v3 = sc_s[r][192 + lane];
        float mx = fmaxf(fmaxf(v0, v1), fmaxf(v2, v3));
        for (int off = 32; off; off >>= 1) mx = fmaxf(mx, __shfl_xor(mx, off));
        float e0 = expf(v0 - mx), e1 = expf(v1 - mx), e2 = expf(v2 - mx), e3 = expf(v3 - mx);
        float sm = e0 + e1 + e2 + e3;
        for (int off = 32; off; off >>= 1) sm += __shfl_xor(sm, off);
        float inv = 1.0f / sm;
        sc_s[r][lane] = e0 * inv;       sc_s[r][64 + lane] = e1 * inv;
        sc_s[r][128 + lane] = e2 * inv; sc_s[r][192 + lane] = e3 * inv;
    }
    for (int c = 0; c < 4; ++c) {
        __syncthreads();
        for (int e = tid; e < 64 * 32; e += 256) {
            int pidx = e >> 5, d2 = e & 31;
            int j = c * 64 + pidx;
            int pos = sel_s[j >> 5] * 16 + (j & 31);
            *(float2*)&chunk[pidx][d2 * 2] =
                *(const float2*)(proj + pos * LDIM + VSLC_OFF + k * DH + d2 * 2);
        }
        __syncthreads();
        for (int p0 = 0; p0 < 64; p0 += 4) {
            float4 sv = *(const float4*)&sc_s[r][c * 64 + p0];
            oslc += sv.x * chunk[p0][lane] + sv.y * chunk[p0+1][lane]
                  + sv.z * chunk[p0+2][lane] + sv.w * chunk[p0+3][lane];
        }
    }

    // ---- sliding-window branch ----
    float owin = 0.0f;
    const int j0 = (t >= 255) ? (t - 255) : 0;
    const int W = t - j0 + 1;
    for (int c = 0; c < 4; ++c) {
        __syncthreads();
        for (int e = tid; e < 64 * 32; e += 256) {
            int pidx = e >> 5, d2 = e & 31;
            int pos = j0 + c * 64 + pidx;
            *(float2*)&chunk[pidx][d2 * 2] =
                *(const float2*)(proj + pos * LDIM + KWIN_OFF + k * DH + d2 * 2);
        }
        __syncthreads();
        int jj = c * 64 + lane;
        float a = 0.0f;
        #pragma unroll
        for (int d2 = 0; d2 < 32; ++d2) {
            float2 qd = *(const float2*)&q_s[r][d2 * 2];
            float2 cd = *(const float2*)&chunk[lane][d2 * 2];
            a += qd.x * cd.x + qd.y * cd.y;
        }
        sc_s[r][jj] = (jj < W) ? a * 0.125f : -1e30f;
    }
    __syncthreads();
    {
        float v0 = sc_s[r][lane],       v1 = sc_s[r][64 + lane];
        float v2 = sc_s[r][128 + lane], v3 = sc_s[r][192 + lane];
        float mx = fmaxf(fmaxf(v0, v1), fmaxf(v2, v3));
        for (int off = 32; off; off >>= 1) mx = fmaxf(mx, __shfl_xor(mx, off));
        float e0 = expf(v0 - mx), e1 = expf(v1 - mx), e2 = expf(v2 - mx), e3 = expf(v3 - mx);
        float sm = e0 + e1 + e2 + e3;
        for (int off = 32; off; off >>= 1) sm += __shfl_xor(sm, off);
        float inv = 1.0f / sm;
        sc_s[r][lane] = e0 * inv;       sc_s[r][64 + lane] = e1 * inv;
        sc_s[r][128 + lane] = e2 * inv; sc_s[r][192 + lane] = e3 * inv;
    }
    for (int c = 0; c < 4; ++c) {
        __syncthreads();
        for (int e = tid; e < 64 * 32; e += 256) {
            int pidx = e >> 5, d2 = e & 31;
            int pos = j0 + c * 64 + pidx;
            *(float2*)&chunk[pidx][d2 * 2] =
                *(const float2*)(proj + pos * LDIM + VWIN_OFF + k * DH + d2 * 2);
        }
        __syncthreads();
        for (int p0 = 0; p0 < 64; p0 += 4) {
            float4 sv = *(const float4*)&sc_s[r][c * 64 + p0];
            owin += sv.x * chunk[p0][lane] + sv.y * chunk[p0+1][lane]
                  + sv.z * chunk[p0+2][lane] + sv.w * chunk[p0+3][lane];
        }
    }

    // ---- gates + write ----
    const int hq = r * NKV + k;
    float g0 = sigmoidf(proj[t * LDIM + hq * 3 + 0]);
    float g1 = sigmoidf(proj[t * LDIM + hq * 3 + 1]);
    float g2 = sigmoidf(proj[t * LDIM + hq * 3 + 2]);
    out[(hq * T_LEN + t) * DH + lane] = g0 * ocmp + g1 * oslc + g2 * owin;
}

extern "C" void kernel_launch(void* const* d_in, const int* in_sizes, int n_in,
                              void* d_out, int out_size, void* d_ws, size_t ws_size,
                              hipStream_t stream) {
    const float* x         = (const float*)d_in[0];
    const float* q         = (const float*)d_in[1];
    const float* gate_w    = (const float*)d_in[2];
    const float* gate_b    = (const float*)d_in[3];
    const float* wk_cmp    = (const float*)d_in[4];
    const float* wv_cmp    = (const float*)d_in[5];
    const float* wk_slc    = (const float*)d_in[6];
    const float* wv_slc    = (const float*)d_in[7];
    const float* wk_win    = (const float*)d_in[8];
    const float* wv_win    = (const float*)d_in[9];
    const float* block_pos = (const float*)d_in[10];
    const float* ck1_w     = (const float*)d_in[11];
    const float* ck1_b     = (const float*)d_in[12];
    const float* ck2_w     = (const float*)d_in[13];
    const float* ck2_b     = (const float*)d_in[14];
    const float* cv1_w     = (const float*)d_in[15];
    const float* cv1_b     = (const float*)d_in[16];
    const float* cv2_w     = (const float*)d_in[17];
    const float* cv2_b     = (const float*)d_in[18];
    float* out = (float*)d_out;

    float* ws   = (float*)d_ws;
    float* proj = ws;                         // 1024*1584 f32
    float* ksum = proj + T_LEN * LDIM;        // 63*4*64
    float* vsum = ksum + NB * NKV * DH;

    dim3 blk(256);
    proj_gemm<<<dim3(25, 16), blk, 0, stream>>>(
        x, gate_w, gate_b, wk_cmp, wv_cmp, wk_slc, wv_slc, wk_win, wv_win, proj);
    gemm_kcmp_f32<<<dim3(4, 16), blk, 0, stream>>>(x, wk_cmp, proj);
    nsa_summarize<<<dim3(NB, NKV, 2), blk, 0, stream>>>(
        proj, block_pos, ck1_w, ck1_b, ck2_w, ck2_b, cv1_w, cv1_b, cv2_w, cv2_b,
        ksum, vsum);
    nsa_fused<<<dim3(T_LEN, NKV), blk, 0, stream>>>(q, proj, ksum, vsum, out);
}

// Round 4
// 429.979 us; speedup vs baseline: 5.8653x; 5.8653x over previous
//
#include <hip/hip_runtime.h>
#include <math.h>

#define T_LEN 1024
#define D_MODEL 1024
#define NKV 4
#define REP 4
#define DH 64
#define NB 63
#define TOPN 8
#define KVD 256        // NKV*DH
#define LDIM 1584      // virtual concatenated width (gemm tiling only)

typedef __attribute__((ext_vector_type(8))) short bf16x8;
typedef __attribute__((ext_vector_type(4))) float f32x4;

__device__ __forceinline__ float gelu_exact(float x) {
    return 0.5f * x * (1.0f + erff(x * 0.70710678118654752f));
}
__device__ __forceinline__ float sigmoidf(float x) {
    return 1.0f / (1.0f + expf(-x));
}
__device__ __forceinline__ unsigned short f2bf(float f) {
    union { float f; unsigned int u; } v; v.f = f;
    unsigned int u = v.u;
    unsigned int r = (u + 0x7FFFu + ((u >> 16) & 1u)) >> 16;  // RNE
    return (unsigned short)r;
}

// ---------------------------------------------------------------------------
// bf16 MFMA GEMM over the virtual concatenation of all 7 projection weights.
// Epilogue routes each output column to its own array (round-1 layouts).
// 64x64 tile, BK=32, grid (25,16).
// ---------------------------------------------------------------------------
__global__ __launch_bounds__(256) void proj_gemm(
    const float* __restrict__ x,
    const float* __restrict__ gate_w, const float* __restrict__ gate_b,
    const float* __restrict__ wk_cmp, const float* __restrict__ wv_cmp,
    const float* __restrict__ wk_slc, const float* __restrict__ wv_slc,
    const float* __restrict__ wk_win, const float* __restrict__ wv_win,
    float* __restrict__ gates_lin,
    float* __restrict__ k_cmp, float* __restrict__ v_cmp,
    float* __restrict__ k_slc, float* __restrict__ v_slc,
    float* __restrict__ k_win, float* __restrict__ v_win)
{
    __shared__ unsigned short As[64][40];
    __shared__ unsigned short Bs[64][40];
    const int tid = threadIdx.x;
    const int lane = tid & 63;
    const int w = tid >> 6;
    const int n0 = blockIdx.x * 64;
    const int m0 = blockIdx.y * 64;

    const int srow = tid >> 2;
    const int sseg = tid & 3;
    const float* ga = x + (m0 + srow) * D_MODEL + sseg * 8;
    const float* gb;
    {
        int nn = n0 + srow;
        if (nn < 48) gb = gate_w + nn * D_MODEL;
        else { nn -= 48;
        if (nn < 256) gb = wk_cmp + nn * D_MODEL;
        else { nn -= 256;
        if (nn < 256) gb = wv_cmp + nn * D_MODEL;
        else { nn -= 256;
        if (nn < 256) gb = wk_slc + nn * D_MODEL;
        else { nn -= 256;
        if (nn < 256) gb = wv_slc + nn * D_MODEL;
        else { nn -= 256;
        if (nn < 256) gb = wk_win + nn * D_MODEL;
        else { nn -= 256;
        if (nn < 256) gb = wv_win + nn * D_MODEL;
        else gb = gate_w; }}}}}}   // cols >= 1584: dummy, masked at store
        gb += sseg * 8;
    }

    f32x4 acc[4] = {};
    const int arow = (w << 4) + (lane & 15);
    const int kk8  = (lane >> 4) * 8;

    for (int k0 = 0; k0 < D_MODEL; k0 += 32) {
        float4 a0 = *(const float4*)(ga + k0);
        float4 a1 = *(const float4*)(ga + k0 + 4);
        float4 b0 = *(const float4*)(gb + k0);
        float4 b1 = *(const float4*)(gb + k0 + 4);
        bf16x8 ap, bp;
        ap[0]=(short)f2bf(a0.x); ap[1]=(short)f2bf(a0.y); ap[2]=(short)f2bf(a0.z); ap[3]=(short)f2bf(a0.w);
        ap[4]=(short)f2bf(a1.x); ap[5]=(short)f2bf(a1.y); ap[6]=(short)f2bf(a1.z); ap[7]=(short)f2bf(a1.w);
        bp[0]=(short)f2bf(b0.x); bp[1]=(short)f2bf(b0.y); bp[2]=(short)f2bf(b0.z); bp[3]=(short)f2bf(b0.w);
        bp[4]=(short)f2bf(b1.x); bp[5]=(short)f2bf(b1.y); bp[6]=(short)f2bf(b1.z); bp[7]=(short)f2bf(b1.w);
        __syncthreads();
        *(bf16x8*)&As[srow][sseg * 8] = ap;
        *(bf16x8*)&Bs[srow][sseg * 8] = bp;
        __syncthreads();
        bf16x8 af = *(bf16x8*)&As[arow][kk8];
        #pragma unroll
        for (int j = 0; j < 4; ++j) {
            bf16x8 bfr = *(bf16x8*)&Bs[j * 16 + (lane & 15)][kk8];
            acc[j] = __builtin_amdgcn_mfma_f32_16x16x32_bf16(af, bfr, acc[j], 0, 0, 0);
        }
    }

    // C/D layout: col = lane&15, row = (lane>>4)*4 + reg  [m89-verified]
    #pragma unroll
    for (int j = 0; j < 4; ++j) {
        int col = n0 + j * 16 + (lane & 15);
        if (col >= LDIM) continue;
        int rbase = m0 + (w << 4) + (lane >> 4) * 4;
        float* dst; int cc; int stride = 256; float badd = 0.0f;
        if (col < 48)        { dst = gates_lin; cc = col;        stride = 48; badd = gate_b[col]; }
        else if (col < 304)  { dst = k_cmp;     cc = col - 48;   }
        else if (col < 560)  { dst = v_cmp;     cc = col - 304;  }
        else if (col < 816)  { dst = k_slc;     cc = col - 560;  }
        else if (col < 1072) { dst = v_slc;     cc = col - 816;  }
        else if (col < 1328) { dst = k_win;     cc = col - 1072; }
        else                 { dst = v_win;     cc = col - 1328; }
        #pragma unroll
        for (int rg = 0; rg < 4; ++rg)
            dst[(rbase + rg) * stride + cc] = acc[j][rg] + badd;
    }
}

// ---------------------------------------------------------------------------
// f32 GEMM for k_cmp only (selection-critical path at f32 precision).
// Overwrites k_cmp (stream-ordered after proj_gemm). grid (4,16).
// ---------------------------------------------------------------------------
__global__ __launch_bounds__(256) void gemm_kcmp_f32(
    const float* __restrict__ A, const float* __restrict__ B,
    float* __restrict__ k_cmp)
{
    __shared__ float As[32][68];
    __shared__ float Bs[32][68];
    const int tid = threadIdx.x;
    const int tx = tid & 15, ty = tid >> 4;
    const int n0 = blockIdx.x * 64, m0 = blockIdx.y * 64;
    const int srow = tid >> 2, sseg = tid & 3;
    const float* ga = A + (m0 + srow) * D_MODEL + sseg * 8;
    const float* gb = B + (n0 + srow) * D_MODEL + sseg * 8;

    float acc[4][4] = {};
    for (int k0 = 0; k0 < D_MODEL; k0 += 32) {
        float4 a0 = *(const float4*)(ga + k0);
        float4 a1 = *(const float4*)(ga + k0 + 4);
        float4 b0 = *(const float4*)(gb + k0);
        float4 b1 = *(const float4*)(gb + k0 + 4);
        __syncthreads();
        As[sseg*8+0][srow]=a0.x; As[sseg*8+1][srow]=a0.y; As[sseg*8+2][srow]=a0.z; As[sseg*8+3][srow]=a0.w;
        As[sseg*8+4][srow]=a1.x; As[sseg*8+5][srow]=a1.y; As[sseg*8+6][srow]=a1.z; As[sseg*8+7][srow]=a1.w;
        Bs[sseg*8+0][srow]=b0.x; Bs[sseg*8+1][srow]=b0.y; Bs[sseg*8+2][srow]=b0.z; Bs[sseg*8+3][srow]=b0.w;
        Bs[sseg*8+4][srow]=b1.x; Bs[sseg*8+5][srow]=b1.y; Bs[sseg*8+6][srow]=b1.z; Bs[sseg*8+7][srow]=b1.w;
        __syncthreads();
        #pragma unroll
        for (int kk = 0; kk < 32; ++kk) {
            float4 a4 = *(const float4*)&As[kk][ty * 4];
            float4 b4 = *(const float4*)&Bs[kk][tx * 4];
            acc[0][0] += a4.x*b4.x; acc[0][1] += a4.x*b4.y; acc[0][2] += a4.x*b4.z; acc[0][3] += a4.x*b4.w;
            acc[1][0] += a4.y*b4.x; acc[1][1] += a4.y*b4.y; acc[1][2] += a4.y*b4.z; acc[1][3] += a4.y*b4.w;
            acc[2][0] += a4.z*b4.x; acc[2][1] += a4.z*b4.y; acc[2][2] += a4.z*b4.z; acc[2][3] += a4.z*b4.w;
            acc[3][0] += a4.w*b4.x; acc[3][1] += a4.w*b4.y; acc[3][2] += a4.w*b4.z; acc[3][3] += a4.w*b4.w;
        }
    }
    #pragma unroll
    for (int i = 0; i < 4; ++i) {
        int m = m0 + ty * 4 + i;
        #pragma unroll
        for (int j = 0; j < 4; ++j) {
            int n = n0 + tx * 4 + j;
            k_cmp[m * KVD + n] = acc[i][j];
        }
    }
}

// ---------------------------------------------------------------------------
// Block summaries. grid (63,4,2)
// ---------------------------------------------------------------------------
__global__ __launch_bounds__(256) void nsa_summarize(
    const float* __restrict__ k_cmp, const float* __restrict__ v_cmp,
    const float* __restrict__ block_pos,
    const float* __restrict__ ck1_w, const float* __restrict__ ck1_b,
    const float* __restrict__ ck2_w, const float* __restrict__ ck2_b,
    const float* __restrict__ cv1_w, const float* __restrict__ cv1_b,
    const float* __restrict__ cv2_w, const float* __restrict__ cv2_b,
    float* __restrict__ ksum, float* __restrict__ vsum)
{
    const int n = blockIdx.x, k = blockIdx.y, which = blockIdx.z;
    const float* src = which ? v_cmp : k_cmp;
    const float* w1  = which ? cv1_w : ck1_w;
    const float* b1  = which ? cv1_b : ck1_b;
    const float* w2  = which ? cv2_w : ck2_w;
    const float* b2  = which ? cv2_b : ck2_b;
    float* dst       = which ? vsum  : ksum;

    __shared__ float flat[32 * DH];
    __shared__ float hidden[DH];
    const int tid = threadIdx.x;
    const int start = n * 16;

    for (int e = tid; e < 512; e += 256) {
        int p = e >> 4, d4 = e & 15;
        float4 s = *(const float4*)(src + ((start + p) * NKV + k) * DH + d4 * 4);
        float4 bp = *(const float4*)(block_pos + p * DH + d4 * 4);
        float4 r; r.x = s.x + bp.x; r.y = s.y + bp.y; r.z = s.z + bp.z; r.w = s.w + bp.w;
        *(float4*)&flat[p * DH + d4 * 4] = r;
    }
    __syncthreads();
    {
        int h = tid >> 2, part = tid & 3;
        const float* wr = w1 + h * 2048 + part * 512;
        const float* fl = flat + part * 512;
        float s = 0.0f;
        for (int j = 0; j < 512; j += 4) {
            float4 a = *(const float4*)(fl + j);
            float4 b = *(const float4*)(wr + j);
            s += a.x * b.x + a.y * b.y + a.z * b.z + a.w * b.w;
        }
        s += __shfl_xor(s, 1);
        s += __shfl_xor(s, 2);
        if (part == 0) hidden[h] = gelu_exact(s + b1[h]);
    }
    __syncthreads();
    {
        int dh = tid >> 2, part = tid & 3;
        const float* wr = w2 + dh * 64 + part * 16;
        float s = 0.0f;
        #pragma unroll
        for (int hh = 0; hh < 16; ++hh) s += hidden[part * 16 + hh] * wr[hh];
        s += __shfl_xor(s, 1);
        s += __shfl_xor(s, 2);
        if (part == 0) dst[(n * NKV + k) * DH + dh] = s + b2[dh];
    }
}

// ---------------------------------------------------------------------------
// Fused attention — EXACT round-1 body (measured VGPR=48, 249 us, 0 conflicts).
// ---------------------------------------------------------------------------
__global__ __launch_bounds__(256) void nsa_fused(
    const float* __restrict__ q,         // (16, T, 64)
    const float* __restrict__ gates_lin, // (T, 48)  pre-sigmoid
    const float* __restrict__ ksum,      // (63, 4, 64)
    const float* __restrict__ vsum,
    const float* __restrict__ k_slc,     // (T, 4, 64)
    const float* __restrict__ v_slc,
    const float* __restrict__ k_win,
    const float* __restrict__ v_win,
    float* __restrict__ out)             // (16, T, 64)
{
    const int t = blockIdx.x;
    const int k = blockIdx.y;
    const int tid = threadIdx.x;
    const int lane = tid & 63;
    const int r = tid >> 6;

    __shared__ float q_s[REP][DH];
    __shared__ float p_cmp_s[REP][64];
    __shared__ float sc_s[REP][256];
    __shared__ float chunk[64][DH + 1];
    __shared__ int   sel_s[TOPN];

    // ---- load q ----
    q_s[r][lane] = q[((r * NKV + k) * T_LEN + t) * DH + lane];
    __syncthreads();

    // ---- compressed scores: lane = block index n ----
    float s = -1e30f;
    if (lane < NB) {
        bool vis = (lane * 16 + 31) <= t;
        if (vis) {
            float acc = 0.0f;
            const float* kr = ksum + (lane * NKV + k) * DH;
            #pragma unroll 16
            for (int d = 0; d < DH; ++d) acc += q_s[r][d] * kr[d];
            s = acc * 0.125f;
        }
    }
    float m = s;
    for (int off = 32; off; off >>= 1) m = fmaxf(m, __shfl_xor(m, off));
    float e = (lane < NB) ? expf(s - m) : 0.0f;
    float sum = e;
    for (int off = 32; off; off >>= 1) sum += __shfl_xor(sum, off);
    float p = e / sum;
    p_cmp_s[r][lane] = (lane < NB) ? p : 0.0f;
    __syncthreads();

    // ---- out_cmp: lane = d ----
    float ocmp = 0.0f;
    if (t >= 31) {
        for (int n = 0; n < NB; ++n)
            ocmp += p_cmp_s[r][n] * vsum[(n * NKV + k) * DH + lane];
    }

    // ---- top-8 selection (wave 0), stable ties ----
    if (r == 0) {
        float imp = (lane < NB)
            ? (p_cmp_s[0][lane] + p_cmp_s[1][lane] + p_cmp_s[2][lane] + p_cmp_s[3][lane])
            : -1e30f;
        const int idx = lane;
        for (int it = 0; it < TOPN; ++it) {
            float v = imp; int i = idx;
            for (int off = 32; off; off >>= 1) {
                float ov = __shfl_xor(v, off);
                int   oi = __shfl_xor(i, off);
                if (ov > v || (ov == v && oi < i)) { v = ov; i = oi; }
            }
            if (lane == 0) sel_s[it] = i;
            if (lane == i) imp = -1e30f;
        }
    }
    __syncthreads();

    // ---- selected branch ----
    float oslc = 0.0f;
    for (int c = 0; c < 4; ++c) {
        __syncthreads();
        for (int e2 = tid; e2 < 64 * DH; e2 += 256) {
            int pidx = e2 >> 6, d = e2 & 63;
            int j = c * 64 + pidx;
            int pos = sel_s[j >> 5] * 16 + (j & 31);
            chunk[pidx][d] = k_slc[(pos * NKV + k) * DH + d];
        }
        __syncthreads();
        int j = c * 64 + lane;
        int pos = sel_s[j >> 5] * 16 + (j & 31);
        float acc = 0.0f;
        #pragma unroll 16
        for (int d = 0; d < DH; ++d) acc += q_s[r][d] * chunk[lane][d];
        sc_s[r][j] = (pos <= t) ? acc * 0.125f : -1e30f;
    }
    __syncthreads();
    {
        float v0 = sc_s[r][lane], v1 = sc_s[r][64 + lane];
        float v2 = sc_s[r][128 + lane], v3 = sc_s[r][192 + lane];
        float mx = fmaxf(fmaxf(v0, v1), fmaxf(v2, v3));
        for (int off = 32; off; off >>= 1) mx = fmaxf(mx, __shfl_xor(mx, off));
        float e0 = expf(v0 - mx), e1 = expf(v1 - mx), e2 = expf(v2 - mx), e3 = expf(v3 - mx);
        float sm = e0 + e1 + e2 + e3;
        for (int off = 32; off; off >>= 1) sm += __shfl_xor(sm, off);
        float inv = 1.0f / sm;
        sc_s[r][lane] = e0 * inv; sc_s[r][64 + lane] = e1 * inv;
        sc_s[r][128 + lane] = e2 * inv; sc_s[r][192 + lane] = e3 * inv;
    }
    for (int c = 0; c < 4; ++c) {
        __syncthreads();
        for (int e2 = tid; e2 < 64 * DH; e2 += 256) {
            int pidx = e2 >> 6, d = e2 & 63;
            int j = c * 64 + pidx;
            int pos = sel_s[j >> 5] * 16 + (j & 31);
            chunk[pidx][d] = v_slc[(pos * NKV + k) * DH + d];
        }
        __syncthreads();
        #pragma unroll 8
        for (int pidx = 0; pidx < 64; ++pidx)
            oslc += sc_s[r][c * 64 + pidx] * chunk[pidx][lane];
    }

    // ---- sliding-window branch ----
    float owin = 0.0f;
    const int j0 = (t >= 255) ? (t - 255) : 0;
    const int W = t - j0 + 1;
    for (int c = 0; c < 4; ++c) {
        __syncthreads();
        for (int e2 = tid; e2 < 64 * DH; e2 += 256) {
            int pidx = e2 >> 6, d = e2 & 63;
            int pos = j0 + c * 64 + pidx;
            chunk[pidx][d] = k_win[(pos * NKV + k) * DH + d];
        }
        __syncthreads();
        int jj = c * 64 + lane;
        float acc = 0.0f;
        #pragma unroll 16
        for (int d = 0; d < DH; ++d) acc += q_s[r][d] * chunk[lane][d];
        sc_s[r][jj] = (jj < W) ? acc * 0.125f : -1e30f;
    }
    __syncthreads();
    {
        float v0 = sc_s[r][lane], v1 = sc_s[r][64 + lane];
        float v2 = sc_s[r][128 + lane], v3 = sc_s[r][192 + lane];
        float mx = fmaxf(fmaxf(v0, v1), fmaxf(v2, v3));
        for (int off = 32; off; off >>= 1) mx = fmaxf(mx, __shfl_xor(mx, off));
        float e0 = expf(v0 - mx), e1 = expf(v1 - mx), e2 = expf(v2 - mx), e3 = expf(v3 - mx);
        float sm = e0 + e1 + e2 + e3;
        for (int off = 32; off; off >>= 1) sm += __shfl_xor(sm, off);
        float inv = 1.0f / sm;
        sc_s[r][lane] = e0 * inv; sc_s[r][64 + lane] = e1 * inv;
        sc_s[r][128 + lane] = e2 * inv; sc_s[r][192 + lane] = e3 * inv;
    }
    for (int c = 0; c < 4; ++c) {
        __syncthreads();
        for (int e2 = tid; e2 < 64 * DH; e2 += 256) {
            int pidx = e2 >> 6, d = e2 & 63;
            int pos = j0 + c * 64 + pidx;
            chunk[pidx][d] = v_win[(pos * NKV + k) * DH + d];
        }
        __syncthreads();
        #pragma unroll 8
        for (int pidx = 0; pidx < 64; ++pidx)
            owin += sc_s[r][c * 64 + pidx] * chunk[pidx][lane];
    }

    // ---- gating + write (lane = d) ----
    const int hq = r * NKV + k;
    const float* gl = gates_lin + t * 48 + hq * 3;
    float g0 = sigmoidf(gl[0]);
    float g1 = sigmoidf(gl[1]);
    float g2 = sigmoidf(gl[2]);
    out[(hq * T_LEN + t) * DH + lane] = g0 * ocmp + g1 * oslc + g2 * owin;
}

extern "C" void kernel_launch(void* const* d_in, const int* in_sizes, int n_in,
                              void* d_out, int out_size, void* d_ws, size_t ws_size,
                              hipStream_t stream) {
    const float* x         = (const float*)d_in[0];
    const float* q         = (const float*)d_in[1];
    const float* gate_w    = (const float*)d_in[2];
    const float* gate_b    = (const float*)d_in[3];
    const float* wk_cmp    = (const float*)d_in[4];
    const float* wv_cmp    = (const float*)d_in[5];
    const float* wk_slc    = (const float*)d_in[6];
    const float* wv_slc    = (const float*)d_in[7];
    const float* wk_win    = (const float*)d_in[8];
    const float* wv_win    = (const float*)d_in[9];
    const float* block_pos = (const float*)d_in[10];
    const float* ck1_w     = (const float*)d_in[11];
    const float* ck1_b     = (const float*)d_in[12];
    const float* ck2_w     = (const float*)d_in[13];
    const float* ck2_b     = (const float*)d_in[14];
    const float* cv1_w     = (const float*)d_in[15];
    const float* cv1_b     = (const float*)d_in[16];
    const float* cv2_w     = (const float*)d_in[17];
    const float* cv2_b     = (const float*)d_in[18];
    float* out = (float*)d_out;

    float* ws = (float*)d_ws;
    float* gates_lin = ws;                         // 1024*48
    float* k_cmp = gates_lin + T_LEN * 48;         // 1024*256 each
    float* v_cmp = k_cmp + T_LEN * KVD;
    float* k_slc = v_cmp + T_LEN * KVD;
    float* v_slc = k_slc + T_LEN * KVD;
    float* k_win = v_slc + T_LEN * KVD;
    float* v_win = k_win + T_LEN * KVD;
    float* ksum  = v_win + T_LEN * KVD;            // 63*4*64 each
    float* vsum  = ksum + NB * KVD;

    dim3 blk(256);
    // all projections in one bf16 MFMA GEMM, routed to separate arrays
    proj_gemm<<<dim3(25, 16), blk, 0, stream>>>(
        x, gate_w, gate_b, wk_cmp, wv_cmp, wk_slc, wv_slc, wk_win, wv_win,
        gates_lin, k_cmp, v_cmp, k_slc, v_slc, k_win, v_win);
    // selection-critical k_cmp recomputed in f32 (overwrites; stream-ordered)
    gemm_kcmp_f32<<<dim3(4, 16), blk, 0, stream>>>(x, wk_cmp, k_cmp);
    // block summaries
    nsa_summarize<<<dim3(NB, NKV, 2), blk, 0, stream>>>(
        k_cmp, v_cmp, block_pos,
        ck1_w, ck1_b, ck2_w, ck2_b, cv1_w, cv1_b, cv2_w, cv2_b,
        ksum, vsum);
    // fused attention + gating (round-1 proven body)
    nsa_fused<<<dim3(T_LEN, NKV), blk, 0, stream>>>(
        q, gates_lin, ksum, vsum, k_slc, v_slc, k_win, v_win, out);
}

// Round 5
// 396.546 us; speedup vs baseline: 6.3598x; 1.0843x over previous
//
#include <hip/hip_runtime.h>
#include <math.h>

#define T_LEN 1024
#define D_MODEL 1024
#define NKV 4
#define REP 4
#define DH 64
#define NB 63
#define TOPN 8
#define KVD 256        // NKV*DH
#define LDIM2 1328     // virtual concatenated width without k_cmp

typedef __attribute__((ext_vector_type(8))) short bf16x8;
typedef __attribute__((ext_vector_type(4))) float f32x4;

__device__ __forceinline__ float gelu_exact(float x) {
    return 0.5f * x * (1.0f + erff(x * 0.70710678118654752f));
}
__device__ __forceinline__ float sigmoidf(float x) {
    return 1.0f / (1.0f + expf(-x));
}
__device__ __forceinline__ unsigned short f2bf(float f) {
    union { float f; unsigned int u; } v; v.f = f;
    unsigned int u = v.u;
    unsigned int r = (u + 0x7FFFu + ((u >> 16) & 1u)) >> 16;  // RNE
    return (unsigned short)r;
}

// ---------------------------------------------------------------------------
// bf16 MFMA GEMM over virtual concat of 6 projections (k_cmp excluded — it is
// recomputed in f32). 64x64 tile, BK=32, grid (21,16).
// ---------------------------------------------------------------------------
__global__ __launch_bounds__(256) void proj_gemm(
    const float* __restrict__ x,
    const float* __restrict__ gate_w, const float* __restrict__ gate_b,
    const float* __restrict__ wv_cmp,
    const float* __restrict__ wk_slc, const float* __restrict__ wv_slc,
    const float* __restrict__ wk_win, const float* __restrict__ wv_win,
    float* __restrict__ gates_lin,
    float* __restrict__ v_cmp,
    float* __restrict__ k_slc, float* __restrict__ v_slc,
    float* __restrict__ k_win, float* __restrict__ v_win)
{
    __shared__ unsigned short As[64][40];
    __shared__ unsigned short Bs[64][40];
    const int tid = threadIdx.x;
    const int lane = tid & 63;
    const int w = tid >> 6;
    const int n0 = blockIdx.x * 64;
    const int m0 = blockIdx.y * 64;

    const int srow = tid >> 2;
    const int sseg = tid & 3;
    const float* ga = x + (m0 + srow) * D_MODEL + sseg * 8;
    const float* gb;
    {
        int nn = n0 + srow;
        if (nn < 48)        gb = gate_w + nn * D_MODEL;
        else if (nn < 304)  gb = wv_cmp + (nn - 48) * D_MODEL;
        else if (nn < 560)  gb = wk_slc + (nn - 304) * D_MODEL;
        else if (nn < 816)  gb = wv_slc + (nn - 560) * D_MODEL;
        else if (nn < 1072) gb = wk_win + (nn - 816) * D_MODEL;
        else if (nn < 1328) gb = wv_win + (nn - 1072) * D_MODEL;
        else                gb = gate_w;   // dummy, masked at store
        gb += sseg * 8;
    }

    f32x4 acc[4] = {};
    const int arow = (w << 4) + (lane & 15);
    const int kk8  = (lane >> 4) * 8;

    for (int k0 = 0; k0 < D_MODEL; k0 += 32) {
        float4 a0 = *(const float4*)(ga + k0);
        float4 a1 = *(const float4*)(ga + k0 + 4);
        float4 b0 = *(const float4*)(gb + k0);
        float4 b1 = *(const float4*)(gb + k0 + 4);
        bf16x8 ap, bp;
        ap[0]=(short)f2bf(a0.x); ap[1]=(short)f2bf(a0.y); ap[2]=(short)f2bf(a0.z); ap[3]=(short)f2bf(a0.w);
        ap[4]=(short)f2bf(a1.x); ap[5]=(short)f2bf(a1.y); ap[6]=(short)f2bf(a1.z); ap[7]=(short)f2bf(a1.w);
        bp[0]=(short)f2bf(b0.x); bp[1]=(short)f2bf(b0.y); bp[2]=(short)f2bf(b0.z); bp[3]=(short)f2bf(b0.w);
        bp[4]=(short)f2bf(b1.x); bp[5]=(short)f2bf(b1.y); bp[6]=(short)f2bf(b1.z); bp[7]=(short)f2bf(b1.w);
        __syncthreads();
        *(bf16x8*)&As[srow][sseg * 8] = ap;
        *(bf16x8*)&Bs[srow][sseg * 8] = bp;
        __syncthreads();
        bf16x8 af = *(bf16x8*)&As[arow][kk8];
        #pragma unroll
        for (int j = 0; j < 4; ++j) {
            bf16x8 bfr = *(bf16x8*)&Bs[j * 16 + (lane & 15)][kk8];
            acc[j] = __builtin_amdgcn_mfma_f32_16x16x32_bf16(af, bfr, acc[j], 0, 0, 0);
        }
    }

    // C/D layout: col = lane&15, row = (lane>>4)*4 + reg  [m89-verified]
    #pragma unroll
    for (int j = 0; j < 4; ++j) {
        int col = n0 + j * 16 + (lane & 15);
        if (col >= LDIM2) continue;
        int rbase = m0 + (w << 4) + (lane >> 4) * 4;
        float* dst; int cc; int stride = 256; float badd = 0.0f;
        if (col < 48)        { dst = gates_lin; cc = col;        stride = 48; badd = gate_b[col]; }
        else if (col < 304)  { dst = v_cmp;     cc = col - 48;   }
        else if (col < 560)  { dst = k_slc;     cc = col - 304;  }
        else if (col < 816)  { dst = v_slc;     cc = col - 560;  }
        else if (col < 1072) { dst = k_win;     cc = col - 816;  }
        else                 { dst = v_win;     cc = col - 1072; }
        #pragma unroll
        for (int rg = 0; rg < 4; ++rg)
            dst[(rbase + rg) * stride + cc] = acc[j][rg] + badd;
    }
}

// ---------------------------------------------------------------------------
// f32 GEMM for k_cmp (selection-critical). Tile 64M x 16N, grid (16,16) =
// 256 workgroups (round-4 version used only 64 -> 25% CU utilization).
// ---------------------------------------------------------------------------
__global__ __launch_bounds__(256) void gemm_kcmp_f32(
    const float* __restrict__ A, const float* __restrict__ B,
    float* __restrict__ k_cmp)
{
    __shared__ float As[32][68];
    __shared__ float Bs[32][20];
    const int tid = threadIdx.x;
    const int tx = tid & 15, ty = tid >> 4;
    const int n0 = blockIdx.x * 16, m0 = blockIdx.y * 64;
    const int srow = tid >> 2, sseg = tid & 3;       // A: 64 rows x 8 floats
    const int srB  = tid >> 4, skB  = (tid & 15) * 2; // B: 16 rows x 2 floats
    const float* ga = A + (m0 + srow) * D_MODEL + sseg * 8;
    const float* gb = B + (n0 + srB) * D_MODEL + skB;

    float acc[4] = {};
    for (int k0 = 0; k0 < D_MODEL; k0 += 32) {
        float4 a0 = *(const float4*)(ga + k0);
        float4 a1 = *(const float4*)(ga + k0 + 4);
        float2 b0 = *(const float2*)(gb + k0);
        __syncthreads();
        As[sseg*8+0][srow]=a0.x; As[sseg*8+1][srow]=a0.y; As[sseg*8+2][srow]=a0.z; As[sseg*8+3][srow]=a0.w;
        As[sseg*8+4][srow]=a1.x; As[sseg*8+5][srow]=a1.y; As[sseg*8+6][srow]=a1.z; As[sseg*8+7][srow]=a1.w;
        Bs[skB][srB] = b0.x; Bs[skB+1][srB] = b0.y;
        __syncthreads();
        #pragma unroll
        for (int kk = 0; kk < 32; ++kk) {
            float4 a4 = *(const float4*)&As[kk][ty * 4];
            float b = Bs[kk][tx];
            acc[0] += a4.x * b; acc[1] += a4.y * b;
            acc[2] += a4.z * b; acc[3] += a4.w * b;
        }
    }
    #pragma unroll
    for (int i = 0; i < 4; ++i)
        k_cmp[(m0 + ty * 4 + i) * KVD + n0 + tx] = acc[i];
}

// ---------------------------------------------------------------------------
// Block summaries. grid (63,4,2). flat[] uses padded 516-float segments so the
// 4 'part' lanes hit banks 0/4/8/12 instead of all bank 0 (round-4: 3.1M
// SQ_LDS_BANK_CONFLICT from the 512-stride layout).
// ---------------------------------------------------------------------------
__global__ __launch_bounds__(256) void nsa_summarize(
    const float* __restrict__ k_cmp, const float* __restrict__ v_cmp,
    const float* __restrict__ block_pos,
    const float* __restrict__ ck1_w, const float* __restrict__ ck1_b,
    const float* __restrict__ ck2_w, const float* __restrict__ ck2_b,
    const float* __restrict__ cv1_w, const float* __restrict__ cv1_b,
    const float* __restrict__ cv2_w, const float* __restrict__ cv2_b,
    float* __restrict__ ksum, float* __restrict__ vsum)
{
    const int n = blockIdx.x, k = blockIdx.y, which = blockIdx.z;
    const float* src = which ? v_cmp : k_cmp;
    const float* w1  = which ? cv1_w : ck1_w;
    const float* b1  = which ? cv1_b : ck1_b;
    const float* w2  = which ? cv2_w : ck2_w;
    const float* b2  = which ? cv2_b : ck2_b;
    float* dst       = which ? vsum  : ksum;

    __shared__ float flat[4 * 516];   // segment s holds j in [512s, 512s+512)
    __shared__ float hidden[DH];
    const int tid = threadIdx.x;
    const int start = n * 16;

    for (int e = tid; e < 512; e += 256) {
        int p = e >> 4, d4 = e & 15;
        float4 s = *(const float4*)(src + ((start + p) * NKV + k) * DH + d4 * 4);
        float4 bp = *(const float4*)(block_pos + p * DH + d4 * 4);
        float4 r; r.x = s.x + bp.x; r.y = s.y + bp.y; r.z = s.z + bp.z; r.w = s.w + bp.w;
        // element j = p*64 + d4*4  ->  addr = (j>>9)*516 + (j&511)
        *(float4*)&flat[(p >> 3) * 516 + (p & 7) * 64 + d4 * 4] = r;
    }
    __syncthreads();
    {
        int h = tid >> 2, part = tid & 3;
        const float* wr = w1 + h * 2048 + part * 512;
        const float* fl = flat + part * 516;
        float s = 0.0f;
        for (int j = 0; j < 512; j += 4) {
            float4 a = *(const float4*)(fl + j);
            float4 b = *(const float4*)(wr + j);
            s += a.x * b.x + a.y * b.y + a.z * b.z + a.w * b.w;
        }
        s += __shfl_xor(s, 1);
        s += __shfl_xor(s, 2);
        if (part == 0) hidden[h] = gelu_exact(s + b1[h]);
    }
    __syncthreads();
    {
        int dh = tid >> 2, part = tid & 3;
        const float* wr = w2 + dh * 64 + part * 16;
        float s = 0.0f;
        #pragma unroll
        for (int hh = 0; hh < 16; ++hh) s += hidden[part * 16 + hh] * wr[hh];
        s += __shfl_xor(s, 1);
        s += __shfl_xor(s, 2);
        if (part == 0) dst[(n * NKV + k) * DH + dh] = s + b2[dh];
    }
}

// ---------------------------------------------------------------------------
// Fused attention — round-1 skeleton + conservative float2 vectorization with
// BOUNDED unrolls (full unroll caused the r2/r3 VGPR=256 spill disaster).
// ---------------------------------------------------------------------------
__global__ __launch_bounds__(256) void nsa_fused(
    const float* __restrict__ q,         // (16, T, 64)
    const float* __restrict__ gates_lin, // (T, 48)  pre-sigmoid
    const float* __restrict__ ksum,      // (63, 4, 64)
    const float* __restrict__ vsum,
    const float* __restrict__ k_slc,     // (T, 4, 64)
    const float* __restrict__ v_slc,
    const float* __restrict__ k_win,
    const float* __restrict__ v_win,
    float* __restrict__ out)             // (16, T, 64)
{
    const int t = blockIdx.x;
    const int k = blockIdx.y;
    const int tid = threadIdx.x;
    const int lane = tid & 63;
    const int r = tid >> 6;

    __shared__ float q_s[REP][DH];
    __shared__ float p_cmp_s[REP][64];
    __shared__ float sc_s[REP][256];
    __shared__ float chunk[64][DH + 2];   // +2: float2-aligned rows, even stride
    __shared__ int   sel_s[TOPN];

    // ---- load q ----
    q_s[r][lane] = q[((r * NKV + k) * T_LEN + t) * DH + lane];
    __syncthreads();

    // ---- compressed scores: lane = block index n ----
    float s = -1e30f;
    if (lane < NB) {
        bool vis = (lane * 16 + 31) <= t;
        if (vis) {
            float acc = 0.0f;
            const float* kr = ksum + (lane * NKV + k) * DH;
            #pragma unroll 16
            for (int d = 0; d < DH; ++d) acc += q_s[r][d] * kr[d];
            s = acc * 0.125f;
        }
    }
    float m = s;
    for (int off = 32; off; off >>= 1) m = fmaxf(m, __shfl_xor(m, off));
    float e = (lane < NB) ? expf(s - m) : 0.0f;
    float sum = e;
    for (int off = 32; off; off >>= 1) sum += __shfl_xor(sum, off);
    float p = e / sum;
    p_cmp_s[r][lane] = (lane < NB) ? p : 0.0f;
    __syncthreads();

    // ---- out_cmp: lane = d ----
    float ocmp = 0.0f;
    if (t >= 31) {
        for (int n = 0; n < NB; ++n)
            ocmp += p_cmp_s[r][n] * vsum[(n * NKV + k) * DH + lane];
    }

    // ---- top-8 selection (wave 0), stable ties ----
    if (r == 0) {
        float imp = (lane < NB)
            ? (p_cmp_s[0][lane] + p_cmp_s[1][lane] + p_cmp_s[2][lane] + p_cmp_s[3][lane])
            : -1e30f;
        const int idx = lane;
        for (int it = 0; it < TOPN; ++it) {
            float v = imp; int i = idx;
            for (int off = 32; off; off >>= 1) {
                float ov = __shfl_xor(v, off);
                int   oi = __shfl_xor(i, off);
                if (ov > v || (ov == v && oi < i)) { v = ov; i = oi; }
            }
            if (lane == 0) sel_s[it] = i;
            if (lane == i) imp = -1e30f;
        }
    }
    __syncthreads();

    // ---- selected branch ----
    float oslc = 0.0f;
    for (int c = 0; c < 4; ++c) {
        __syncthreads();
        for (int e2 = tid; e2 < 64 * 32; e2 += 256) {
            int pidx = e2 >> 5, d2 = e2 & 31;
            int j = c * 64 + pidx;
            int pos = sel_s[j >> 5] * 16 + (j & 31);
            *(float2*)&chunk[pidx][d2 * 2] =
                *(const float2*)&k_slc[(pos * NKV + k) * DH + d2 * 2];
        }
        __syncthreads();
        int j = c * 64 + lane;
        int pos = sel_s[j >> 5] * 16 + (j & 31);
        float acc = 0.0f;
        #pragma unroll 8
        for (int d2 = 0; d2 < 32; ++d2) {
            float2 qd = *(const float2*)&q_s[r][d2 * 2];
            float2 cd = *(const float2*)&chunk[lane][d2 * 2];
            acc += qd.x * cd.x + qd.y * cd.y;
        }
        sc_s[r][j] = (pos <= t) ? acc * 0.125f : -1e30f;
    }
    __syncthreads();
    {
        float v0 = sc_s[r][lane], v1 = sc_s[r][64 + lane];
        float v2 = sc_s[r][128 + lane], v3 = sc_s[r][192 + lane];
        float mx = fmaxf(fmaxf(v0, v1), fmaxf(v2, v3));
        for (int off = 32; off; off >>= 1) mx = fmaxf(mx, __shfl_xor(mx, off));
        float e0 = expf(v0 - mx), e1 = expf(v1 - mx), e2 = expf(v2 - mx), e3 = expf(v3 - mx);
        float sm = e0 + e1 + e2 + e3;
        for (int off = 32; off; off >>= 1) sm += __shfl_xor(sm, off);
        float inv = 1.0f / sm;
        sc_s[r][lane] = e0 * inv; sc_s[r][64 + lane] = e1 * inv;
        sc_s[r][128 + lane] = e2 * inv; sc_s[r][192 + lane] = e3 * inv;
    }
    for (int c = 0; c < 4; ++c) {
        __syncthreads();
        for (int e2 = tid; e2 < 64 * 32; e2 += 256) {
            int pidx = e2 >> 5, d2 = e2 & 31;
            int j = c * 64 + pidx;
            int pos = sel_s[j >> 5] * 16 + (j & 31);
            *(float2*)&chunk[pidx][d2 * 2] =
                *(const float2*)&v_slc[(pos * NKV + k) * DH + d2 * 2];
        }
        __syncthreads();
        #pragma unroll 4
        for (int p0 = 0; p0 < 64; p0 += 2) {
            float2 sv = *(const float2*)&sc_s[r][c * 64 + p0];
            oslc += sv.x * chunk[p0][lane] + sv.y * chunk[p0 + 1][lane];
        }
    }

    // ---- sliding-window branch ----
    float owin = 0.0f;
    const int j0 = (t >= 255) ? (t - 255) : 0;
    const int W = t - j0 + 1;
    for (int c = 0; c < 4; ++c) {
        __syncthreads();
        for (int e2 = tid; e2 < 64 * 32; e2 += 256) {
            int pidx = e2 >> 5, d2 = e2 & 31;
            int pos = j0 + c * 64 + pidx;
            *(float2*)&chunk[pidx][d2 * 2] =
                *(const float2*)&k_win[(pos * NKV + k) * DH + d2 * 2];
        }
        __syncthreads();
        int jj = c * 64 + lane;
        float acc = 0.0f;
        #pragma unroll 8
        for (int d2 = 0; d2 < 32; ++d2) {
            float2 qd = *(const float2*)&q_s[r][d2 * 2];
            float2 cd = *(const float2*)&chunk[lane][d2 * 2];
            acc += qd.x * cd.x + qd.y * cd.y;
        }
        sc_s[r][jj] = (jj < W) ? acc * 0.125f : -1e30f;
    }
    __syncthreads();
    {
        float v0 = sc_s[r][lane], v1 = sc_s[r][64 + lane];
        float v2 = sc_s[r][128 + lane], v3 = sc_s[r][192 + lane];
        float mx = fmaxf(fmaxf(v0, v1), fmaxf(v2, v3));
        for (int off = 32; off; off >>= 1) mx = fmaxf(mx, __shfl_xor(mx, off));
        float e0 = expf(v0 - mx), e1 = expf(v1 - mx), e2 = expf(v2 - mx), e3 = expf(v3 - mx);
        float sm = e0 + e1 + e2 + e3;
        for (int off = 32; off; off >>= 1) sm += __shfl_xor(sm, off);
        float inv = 1.0f / sm;
        sc_s[r][lane] = e0 * inv; sc_s[r][64 + lane] = e1 * inv;
        sc_s[r][128 + lane] = e2 * inv; sc_s[r][192 + lane] = e3 * inv;
    }
    for (int c = 0; c < 4; ++c) {
        __syncthreads();
        for (int e2 = tid; e2 < 64 * 32; e2 += 256) {
            int pidx = e2 >> 5, d2 = e2 & 31;
            int pos = j0 + c * 64 + pidx;
            *(float2*)&chunk[pidx][d2 * 2] =
                *(const float2*)&v_win[(pos * NKV + k) * DH + d2 * 2];
        }
        __syncthreads();
        #pragma unroll 4
        for (int p0 = 0; p0 < 64; p0 += 2) {
            float2 sv = *(const float2*)&sc_s[r][c * 64 + p0];
            owin += sv.x * chunk[p0][lane] + sv.y * chunk[p0 + 1][lane];
        }
    }

    // ---- gating + write (lane = d) ----
    const int hq = r * NKV + k;
    const float* gl = gates_lin + t * 48 + hq * 3;
    float g0 = sigmoidf(gl[0]);
    float g1 = sigmoidf(gl[1]);
    float g2 = sigmoidf(gl[2]);
    out[(hq * T_LEN + t) * DH + lane] = g0 * ocmp + g1 * oslc + g2 * owin;
}

extern "C" void kernel_launch(void* const* d_in, const int* in_sizes, int n_in,
                              void* d_out, int out_size, void* d_ws, size_t ws_size,
                              hipStream_t stream) {
    const float* x         = (const float*)d_in[0];
    const float* q         = (const float*)d_in[1];
    const float* gate_w    = (const float*)d_in[2];
    const float* gate_b    = (const float*)d_in[3];
    const float* wk_cmp    = (const float*)d_in[4];
    const float* wv_cmp    = (const float*)d_in[5];
    const float* wk_slc    = (const float*)d_in[6];
    const float* wv_slc    = (const float*)d_in[7];
    const float* wk_win    = (const float*)d_in[8];
    const float* wv_win    = (const float*)d_in[9];
    const float* block_pos = (const float*)d_in[10];
    const float* ck1_w     = (const float*)d_in[11];
    const float* ck1_b     = (const float*)d_in[12];
    const float* ck2_w     = (const float*)d_in[13];
    const float* ck2_b     = (const float*)d_in[14];
    const float* cv1_w     = (const float*)d_in[15];
    const float* cv1_b     = (const float*)d_in[16];
    const float* cv2_w     = (const float*)d_in[17];
    const float* cv2_b     = (const float*)d_in[18];
    float* out = (float*)d_out;

    float* ws = (float*)d_ws;
    float* gates_lin = ws;                         // 1024*48
    float* k_cmp = gates_lin + T_LEN * 48;         // 1024*256 each
    float* v_cmp = k_cmp + T_LEN * KVD;
    float* k_slc = v_cmp + T_LEN * KVD;
    float* v_slc = k_slc + T_LEN * KVD;
    float* k_win = v_slc + T_LEN * KVD;
    float* v_win = k_win + T_LEN * KVD;
    float* ksum  = v_win + T_LEN * KVD;            // 63*4*64 each
    float* vsum  = ksum + NB * KVD;

    dim3 blk(256);
    // 6 projections in one bf16 MFMA GEMM (k_cmp excluded)
    proj_gemm<<<dim3(21, 16), blk, 0, stream>>>(
        x, gate_w, gate_b, wv_cmp, wk_slc, wv_slc, wk_win, wv_win,
        gates_lin, v_cmp, k_slc, v_slc, k_win, v_win);
    // selection-critical k_cmp in f32, 256 workgroups
    gemm_kcmp_f32<<<dim3(16, 16), blk, 0, stream>>>(x, wk_cmp, k_cmp);
    // block summaries (conflict-free padded LDS)
    nsa_summarize<<<dim3(NB, NKV, 2), blk, 0, stream>>>(
        k_cmp, v_cmp, block_pos,
        ck1_w, ck1_b, ck2_w, ck2_b, cv1_w, cv1_b, cv2_w, cv2_b,
        ksum, vsum);
    // fused attention + gating
    nsa_fused<<<dim3(T_LEN, NKV), blk, 0, stream>>>(
        q, gates_lin, ksum, vsum, k_slc, v_slc, k_win, v_win, out);
}